// Round 1
// 1556.840 us; speedup vs baseline: 1.1187x; 1.1187x over previous
//
#include <hip/hip_runtime.h>
#include <stdint.h>

#define ALPHA 0.1f
#define NN 20000
#define DF 768
#define NE 200000
#define NB 64
#define TSEQ 128
#define SF 128
#define HS 512
#define NCLS 14

typedef __attribute__((ext_vector_type(8))) short short8;
typedef __attribute__((ext_vector_type(4))) float f32x4;
typedef __attribute__((ext_vector_type(4))) unsigned int u32x4;

// ---------------- workspace layout (bytes) ----------------
#define OFF_DEG     0u           // int[20000]
#define OFF_CSRC    80000u       // int[20000]
#define OFF_CNTB    160000u      // int[64]
#define OFF_FLAG64  176640u      // int[1] : 1 if indices are int64
#define ZERO_INTS   44161u       // zero [0, 176644)
#define OFF_ROWPTR  176896u      // int[20001]
#define OFF_CURSOR  257024u      // int[20000]
#define OFF_DINV    337024u      // float[20000]
#define OFF_COL     417024u      // int[200000]
#define OFF_WGT     1217024u     // float[200000]
#define OFF_V0      2017280u     // float[20000*64]
#define OFF_V1      7137280u     // float[20000*64]
#define OFF_HBUF    12257280u    // u32 [2][2][64][512]  (tag<<16 | bf16 h)
#define OFF_YSEQ    12781568u    // float[64*1024]
#define OFF_SH1     13043712u    // float[64*512]
#define OFF_SH2     13174784u    // float[64*256]
#define OFF_PART    13240320u    // float[16][64][768]
#define OFF_POOL    16386048u    // float[64*768]
#define OFF_GH1     16582656u    // float[64*384]
#define OFF_GH2     16680960u    // float[64*192]

__device__ __forceinline__ unsigned short f2b(float f) {
  union { float f; unsigned u; } v; v.f = f;
  unsigned u = v.u;
  return (unsigned short)((u + 0x7FFFu + ((u >> 16) & 1u)) >> 16);
}

__device__ __forceinline__ int idx_at(const int* p, long long i, int mode64) {
  return mode64 ? p[2*i] : p[i];   // little-endian low word
}

// ---------------- small utility kernels ----------------
__global__ void zero_ints_kernel(int* p, int n) {
  int i = blockIdx.x * blockDim.x + threadIdx.x;
  if (i < n) p[i] = 0;
}

__global__ void detect_i64_kernel(const int* e, int* flag) {
  if (threadIdx.x == 0 && blockIdx.x == 0) {
    int all0 = 1;
    for (int i = 0; i < 256; ++i) if (e[2*i + 1] != 0) { all0 = 0; break; }
    *flag = all0;
  }
}

__global__ void hist_kernel(const int* e, const int* batch, int* deg, int* csrc,
                            int* cntb, const int* flag) {
  int i = blockIdx.x * blockDim.x + threadIdx.x;
  int m = *flag;
  if (i < NE) {
    int s = idx_at(e, i, m);
    int d = idx_at(e, (long long)NE + i, m);
    atomicAdd(&csrc[s], 1);
    atomicAdd(&deg[d], 1);
  }
  if (i < NN) atomicAdd(&cntb[idx_at(batch, i, m)], 1);
}

__global__ void dinv_kernel(const int* deg, float* dinv) {
  int i = blockIdx.x * blockDim.x + threadIdx.x;
  if (i < NN) dinv[i] = rsqrtf((float)(deg[i] + 1));   // +1 self loop, >=1
}

__global__ void scan_kernel(const int* cnt, int* row_ptr, int* cursor) {
  __shared__ int sA[1024], sB[1024];
  int tid = threadIdx.x;
  int carry = 0;
  const int nch = (NN + 1023) / 1024;
  for (int c = 0; c < nch; ++c) {
    int i = c * 1024 + tid;
    int v = (i < NN) ? cnt[i] : 0;
    sA[tid] = v;
    __syncthreads();
    int* src = sA; int* dst = sB;
    for (int off = 1; off < 1024; off <<= 1) {
      dst[tid] = src[tid] + (tid >= off ? src[tid - off] : 0);
      __syncthreads();
      int* t = src; src = dst; dst = t;
    }
    if (i < NN) { int ex = carry + src[tid] - v; row_ptr[i] = ex; cursor[i] = ex; }
    carry += src[1023];
    __syncthreads();
  }
  if (tid == 0) row_ptr[NN] = carry;
}

__global__ void fill_kernel(const int* e, const float* dinv, int* cursor,
                            int* colA, float* wgt, const int* flag) {
  int i = blockIdx.x * blockDim.x + threadIdx.x;
  if (i >= NE) return;
  int m = *flag;
  int s = idx_at(e, i, m);
  int d = idx_at(e, (long long)NE + i, m);
  int pos = atomicAdd(&cursor[s], 1);
  colA[pos] = d;
  wgt[pos] = dinv[s] * dinv[d];
}

__global__ void v0init_kernel(const int* batch, float* v0, const int* flag) {
  int i = blockIdx.x * blockDim.x + threadIdx.x;
  if (i >= NN * 64) return;
  int n = i >> 6, b = i & 63;
  v0[i] = (idx_at(batch, n, *flag) == b) ? 1.0f : 0.0f;
}

// one wave per node, lane = graph id (64 == wave width); 4-edge ILP
__global__ void hop_kernel(const float* __restrict__ vin, float* __restrict__ vout,
                           const int* __restrict__ row_ptr, const int* __restrict__ colA,
                           const float* __restrict__ wgt, const float* __restrict__ dinv,
                           const int* __restrict__ batch, const int* __restrict__ flag) {
  int wid = (blockIdx.x * blockDim.x + threadIdx.x) >> 6;
  int lane = threadIdx.x & 63;
  if (wid >= NN) return;
  float di = dinv[wid];
  float acc = di * di * vin[wid * 64 + lane];
  int e0 = row_ptr[wid], e1 = row_ptr[wid + 1];
  int e = e0;
  for (; e + 4 <= e1; e += 4) {
    int c0 = colA[e], c1 = colA[e + 1], c2 = colA[e + 2], c3 = colA[e + 3];
    float w0 = wgt[e], w1 = wgt[e + 1], w2 = wgt[e + 2], w3 = wgt[e + 3];
    float v0 = vin[(size_t)c0 * 64 + lane];
    float v1 = vin[(size_t)c1 * 64 + lane];
    float v2 = vin[(size_t)c2 * 64 + lane];
    float v3 = vin[(size_t)c3 * 64 + lane];
    acc += w0 * v0 + w1 * v1 + w2 * v2 + w3 * v3;
  }
  for (; e < e1; ++e) acc += wgt[e] * vin[(size_t)colA[e] * 64 + lane];
  float y0 = (idx_at(batch, wid, *flag) == lane) ? ALPHA : 0.0f;
  vout[wid * 64 + lane] = (1.0f - ALPHA) * acc + y0;
}

// pooled_unnorm partials: 48 f-tiles x 16 node-chunks, lane = graph id
__global__ void spmm_kernel(const float* __restrict__ S, const float* __restrict__ x,
                            float* __restrict__ partial) {
  int wid = (blockIdx.x * blockDim.x + threadIdx.x) >> 6;   // 768 waves
  int lane = threadIdx.x & 63;
  int ft = wid % 48, ch = wid / 48;
  if (ch >= 16) return;
  int f0 = ft * 16;
  int n0 = ch * 1250, n1 = n0 + 1250;
  float acc[16];
#pragma unroll
  for (int f = 0; f < 16; ++f) acc[f] = 0.0f;
  for (int n = n0; n < n1; ++n) {
    float sv = S[n * 64 + lane];
    const float* xr = x + (size_t)n * DF + f0;
#pragma unroll
    for (int f = 0; f < 16; ++f) acc[f] += sv * xr[f];
  }
  float* pr = partial + ((size_t)(ch * 64 + lane)) * DF + f0;
#pragma unroll
  for (int f = 0; f < 16; ++f) pr[f] = acc[f];
}

__global__ void reduce_pool_kernel(const float* __restrict__ partial, const int* __restrict__ cntb,
                                   float* __restrict__ pooled) {
  int i = blockIdx.x * blockDim.x + threadIdx.x;
  if (i >= 64 * DF) return;
  int b = i / DF, f = i - b * DF;
  float s = 0.0f;
  for (int c = 0; c < 16; ++c) s += partial[((size_t)(c * 64 + b)) * DF + f];
  int cnt = cntb[b]; if (cnt < 1) cnt = 1;
  pooled[i] = s / (float)cnt;
}

// C[M,N] = act(A[M,K] @ W[N,K]^T + bias), optionally accumulate into C
__global__ void mlp_layer_kernel(const float* __restrict__ A, const float* __restrict__ W,
                                 const float* __restrict__ bias, float* __restrict__ C,
                                 int M, int N, int K, int relu, int accum) {
  int i = blockIdx.x * blockDim.x + threadIdx.x;
  if (i >= M * N) return;
  int mrow = i / N, n = i - mrow * N;
  float acc = bias[n];
  const float4* a4 = (const float4*)(A + (size_t)mrow * K);
  const float4* w4 = (const float4*)(W + (size_t)n * K);
  int k4 = K >> 2;
#pragma unroll 4
  for (int k = 0; k < k4; ++k) {
    float4 av = a4[k], wv = w4[k];
    acc += av.x * wv.x + av.y * wv.y + av.z * wv.z + av.w * wv.w;
  }
  if (relu) acc = fmaxf(acc, 0.0f);
  if (accum) C[i] += acc; else C[i] = acc;
}

// ---------------- GRU recurrent kernel (direction-decoupled) ----------------
// 512 blocks x 192 threads: blockIdx = d*256 + g*32 + rk.
//   d  = direction (0 fwd, 1 bwd)   — the two recurrence chains are
//        independent, so they get separate blocks and run CONCURRENTLY
//        (2 blocks/CU: LDS 74.6 KB x2 = 149.2 KB <= 160 KB). This removes
//        one of the two serialized MALL round trips per timestep that the
//        previous (coupled fwd/bwd) kernel paid.
//   g  = sequence group (8 seqs), rk = rank (16 h-cols).
// LDS (one dir only): W1[48][648] bf16 (r/z/n weight slices), hl[8][648]
// bf16 ([h|x] A-rows), ghs[64][8] f32 gate staging.
// Exchange: h stored to hbuf as (tag<<16|bf16) via relaxed agent atomics,
// double-buffered on t&1. Consumers poll with global_load_dwordx4 sc0 sc1
// (L1+L2 bypass == agent-scope semantics; each u32 carries its own tag so
// no cross-word atomicity is needed) and a per-thread got-bitmask so each
// chunk is loaded until matched, then written to LDS and never re-polled:
// <=6 wide loads per sweep instead of 22 scalar atomic loads.
#define GRU_LDS_BYTES 74624   // 48*648*2 + 8*648*2 + 64*8*4

__global__ __launch_bounds__(192, 1) void gru_kernel(
    const float* __restrict__ seq,
    const float* __restrict__ wih_f, const float* __restrict__ whh_f,
    const float* __restrict__ bih_f, const float* __restrict__ bhh_f,
    const float* __restrict__ wih_b, const float* __restrict__ whh_b,
    const float* __restrict__ bih_b, const float* __restrict__ bhh_b,
    unsigned* __restrict__ hbuf, float* __restrict__ y_seq) {
  extern __shared__ char smem_raw[];
  unsigned short* W1 = (unsigned short*)smem_raw;     // [48][648]
  unsigned short* hl = W1 + 48 * 648;                 // [8][648]
  float* ghs = (float*)(hl + 8 * 648);                // [64][8]

  const int tid = threadIdx.x;            // 0..191
  const int wave = tid >> 6, lane = tid & 63;
  const int quad = lane >> 4, l15 = lane & 15;
  const int d  = blockIdx.x >> 8;         // 0 fwd, 1 bwd
  const int g  = (blockIdx.x >> 5) & 7;   // 8 groups
  const int rk = blockIdx.x & 31;         // 32 ranks
  const int seqbase = g * 8;
  const int c0 = rk * 16;

  const float* WHHd = d ? whh_b : whh_f;
  const float* WIHd = d ? wih_b : wih_f;
  const float* BIHd = d ? bih_b : bih_f;
  const float* BHHd = d ? bhh_b : bhh_f;

  // ---- stationary weights -> LDS (fp32 -> bf16), one direction ----
  for (int i = tid; i < 48 * 640; i += 192) {
    int rrow = i / 640;
    int c = i - rrow * 640;
    int gcol = (rrow < 16) ? (c0 + rrow)
             : (rrow < 32) ? (512 + c0 + (rrow - 16))
                           : (1024 + c0 + (rrow - 32));
    float val = (c < 512) ? WHHd[gcol * 512 + c] : WIHd[gcol * 128 + (c - 512)];
    W1[rrow * 648 + c] = f2b(val);
  }
  // ---- hl init: h(0)=0; stage x(0) ----
  for (int i = tid; i < 8 * 512; i += 192) {
    int s = i >> 9, c = i & 511;
    hl[s * 648 + c] = 0;
  }
  {
    int tt = d ? 127 : 0;
    for (int i = tid; i < 8 * 128; i += 192) {
      int s = i >> 7, k = i & 127;
      hl[s * 648 + 512 + k] =
          f2b(seq[(size_t)(seqbase + s) * (TSEQ * SF) + tt * SF + k]);
    }
  }

  float b_r = 0, b_z = 0, b_in = 0, b_hn = 0;
  float hprev = 0, msum = 0, mx = -1e30f;
  const int seq_i = (tid >> 4) & 7, col_i = tid & 15;
  if (tid < 128) {
    b_r  = BIHd[c0 + col_i] + BHHd[c0 + col_i];
    b_z  = BIHd[512 + c0 + col_i] + BHHd[512 + c0 + col_i];
    b_in = BIHd[1024 + c0 + col_i];
    b_hn = BHHd[1024 + c0 + col_i];
  }
  __syncthreads();

  // wave role: 0=r, 1=z, 2=n
  auto do_gemm = [&]() {
    f32x4 accH = {0, 0, 0, 0}, accX = {0, 0, 0, 0};
    const unsigned short* arow = hl + (l15 & 7) * 648 + quad * 8;  // rows 8-15 dup rows 0-7 (discarded)
    const unsigned short* brow = W1 + (wave * 16 + l15) * 648 + quad * 8;
    if (wave < 2) {           // r or z: fused K=640 over [h|x]
#pragma unroll
      for (int kc = 0; kc < 20; ++kc)
        accH = __builtin_amdgcn_mfma_f32_16x16x32_bf16(
            *(const short8*)(arow + kc * 32), *(const short8*)(brow + kc * 32),
            accH, 0, 0, 0);
      float* gd = ghs + (wave * 16 + l15) * 8;
#pragma unroll
      for (int rr = 0; rr < 4; ++rr) { int m = quad * 4 + rr; if (m < 8) gd[m] = accH[rr]; }
    } else {                  // n: h-part (K=512) and x-part (K=128) separate
#pragma unroll
      for (int kc = 0; kc < 16; ++kc)
        accH = __builtin_amdgcn_mfma_f32_16x16x32_bf16(
            *(const short8*)(arow + kc * 32), *(const short8*)(brow + kc * 32),
            accH, 0, 0, 0);
#pragma unroll
      for (int kc = 0; kc < 4; ++kc)
        accX = __builtin_amdgcn_mfma_f32_16x16x32_bf16(
            *(const short8*)(arow + 512 + kc * 32), *(const short8*)(brow + 512 + kc * 32),
            accX, 0, 0, 0);
      float* gdh = ghs + (32 + l15) * 8;
      float* gdx = ghs + (48 + l15) * 8;
#pragma unroll
      for (int rr = 0; rr < 4; ++rr) {
        int m = quad * 4 + rr;
        if (m < 8) { gdh[m] = accH[rr]; gdx[m] = accX[rr]; }
      }
    }
  };

  // gather h(tagexp) into hl + stage x(t_x); run by all 192 threads
  auto do_gather_stage = [&](int t_x, int slot, unsigned tagexp) {
    // stage x first (independent global loads overlap the tag-poll)
    {
      int tt = d ? (127 - t_x) : t_x;
#pragma unroll
      for (int j = 0; j < 6; ++j) {
        int flat = tid + 192 * j;
        if (flat < 1024) {
          int s = flat >> 7, k = flat & 127;
          hl[s * 648 + 512 + k] =
              f2b(seq[(size_t)(seqbase + s) * (TSEQ * SF) + tt * SF + k]);
        }
      }
    }
    const unsigned* hb = hbuf + ((size_t)(slot * 2 + d) * 64 + seqbase) * 512;
    unsigned got = (tid < 64) ? 0u : 0x20u;   // chunk 5 invalid for tid>=64
    int guard = 0;

#define ISSUE(J, VV)                                                          \
    if (!(got & (1u << J)))                                                   \
      asm volatile("global_load_dwordx4 %0, %1, off sc0 sc1"                  \
                   : "=v"(VV) : "v"(hb + (unsigned)(tid + 192 * J) * 4)       \
                   : "memory");
#define CHECK(J, VV)                                                          \
    if (!(got & (1u << J))) {                                                 \
      if ((VV[0] >> 16) == tagexp && (VV[1] >> 16) == tagexp &&               \
          (VV[2] >> 16) == tagexp && (VV[3] >> 16) == tagexp) {               \
        int flat = (tid + 192 * J) * 4;                                       \
        unsigned* dp = (unsigned*)(hl + (flat >> 9) * 648 + (flat & 511));    \
        dp[0] = (VV[0] & 0xFFFFu) | (VV[1] << 16);                            \
        dp[1] = (VV[2] & 0xFFFFu) | (VV[3] << 16);                            \
        got |= 1u << J;                                                       \
      }                                                                       \
    }

    for (;;) {
      u32x4 v0, v1, v2, v3, v4, v5;
      ISSUE(0, v0) ISSUE(1, v1) ISSUE(2, v2)
      ISSUE(3, v3) ISSUE(4, v4) ISSUE(5, v5)
      asm volatile("s_waitcnt vmcnt(0)" ::: "memory");
      __builtin_amdgcn_sched_barrier(0);
      CHECK(0, v0) CHECK(1, v1) CHECK(2, v2)
      CHECK(3, v3) CHECK(4, v4) CHECK(5, v5)
      if (got == 0x3Fu) break;
      if (++guard > (1 << 18)) break;
      __builtin_amdgcn_s_sleep(1);
    }
#undef ISSUE
#undef CHECK
  };

  for (int t = 0; t < 128; ++t) {
    do_gemm();
    __syncthreads();
    if (tid < 128) {
      const float* gd = ghs;
      float gr = gd[col_i * 8 + seq_i];
      float gz = gd[(16 + col_i) * 8 + seq_i];
      float gh = gd[(32 + col_i) * 8 + seq_i];
      float gx = gd[(48 + col_i) * 8 + seq_i];
      float r = 1.0f / (1.0f + __expf(-(gr + b_r)));
      float z = 1.0f / (1.0f + __expf(-(gz + b_z)));
      float narg = gx + b_in + r * (gh + b_hn);
      float e2 = __expf(-2.0f * fabsf(narg));
      float nt = (1.0f - e2) / (1.0f + e2);
      nt = (narg < 0.0f) ? -nt : nt;
      float h2 = (1.0f - z) * nt + z * hprev;
      hprev = h2; msum += h2; mx = fmaxf(mx, h2);
      if (t < 127) {
        unsigned pk = ((unsigned)(t + 1) << 16) | (unsigned)f2b(h2);
        __hip_atomic_store(
            &hbuf[((size_t)((((t + 1) & 1) * 2 + d) * 64 + seqbase + seq_i)) * 512 +
                  (c0 + col_i)],
            pk, __ATOMIC_RELAXED, __HIP_MEMORY_SCOPE_AGENT);
      }
    }
    if (t < 127) do_gather_stage(t + 1, (t + 1) & 1, (unsigned)(t + 1));
    __syncthreads();
  }

  if (tid < 128) {   // seq1 + seq2 = mean + max over T
    y_seq[(size_t)(seqbase + seq_i) * 1024 + d * 512 + c0 + col_i] =
        msum * (1.0f / 128.0f) + mx;
  }
}

// ---------------- launcher ----------------
extern "C" void kernel_launch(void* const* d_in, const int* in_sizes, int n_in,
                              void* d_out, int out_size, void* d_ws, size_t ws_size,
                              hipStream_t stream) {
  const float* x      = (const float*)d_in[0];
  const int*   eidx   = (const int*)d_in[1];
  const float* seq    = (const float*)d_in[2];
  const int*   batch  = (const int*)d_in[3];
  const float* wih_f  = (const float*)d_in[4];
  const float* whh_f  = (const float*)d_in[5];
  const float* bih_f  = (const float*)d_in[6];
  const float* bhh_f  = (const float*)d_in[7];
  const float* wih_b  = (const float*)d_in[8];
  const float* whh_b  = (const float*)d_in[9];
  const float* bih_b  = (const float*)d_in[10];
  const float* bhh_b  = (const float*)d_in[11];
  const float* mg_w0  = (const float*)d_in[12];
  const float* mg_b0  = (const float*)d_in[13];
  const float* mg_w1  = (const float*)d_in[14];
  const float* mg_b1  = (const float*)d_in[15];
  const float* mg_w2  = (const float*)d_in[16];
  const float* mg_b2  = (const float*)d_in[17];
  const float* ms_w0  = (const float*)d_in[18];
  const float* ms_b0  = (const float*)d_in[19];
  const float* ms_w1  = (const float*)d_in[20];
  const float* ms_b1  = (const float*)d_in[21];
  const float* ms_w2  = (const float*)d_in[22];
  const float* ms_b2  = (const float*)d_in[23];
  float* out = (float*)d_out;
  char* ws = (char*)d_ws;

  int*   deg     = (int*)(ws + OFF_DEG);
  int*   csrc    = (int*)(ws + OFF_CSRC);
  int*   cntb    = (int*)(ws + OFF_CNTB);
  int*   flag    = (int*)(ws + OFF_FLAG64);
  int*   row_ptr = (int*)(ws + OFF_ROWPTR);
  int*   cursor  = (int*)(ws + OFF_CURSOR);
  float* dinv    = (float*)(ws + OFF_DINV);
  int*   colA    = (int*)(ws + OFF_COL);
  float* wgtA    = (float*)(ws + OFF_WGT);
  float* V0      = (float*)(ws + OFF_V0);
  float* V1      = (float*)(ws + OFF_V1);
  unsigned* hbuf = (unsigned*)(ws + OFF_HBUF);
  float* y_seq   = (float*)(ws + OFF_YSEQ);
  float* sh1     = (float*)(ws + OFF_SH1);
  float* sh2     = (float*)(ws + OFF_SH2);
  float* part    = (float*)(ws + OFF_PART);
  float* pooled  = (float*)(ws + OFF_POOL);
  float* gh1     = (float*)(ws + OFF_GH1);
  float* gh2     = (float*)(ws + OFF_GH2);

  hipFuncSetAttribute((const void*)gru_kernel,
                      hipFuncAttributeMaxDynamicSharedMemorySize, GRU_LDS_BYTES);

  // ---- graph prep (CSR for A^T, degrees, batch counts) ----
  zero_ints_kernel<<<(ZERO_INTS + 255) / 256, 256, 0, stream>>>((int*)ws, (int)ZERO_INTS);
  detect_i64_kernel<<<1, 64, 0, stream>>>(eidx, flag);
  hist_kernel<<<(NE + 255) / 256, 256, 0, stream>>>(eidx, batch, deg, csrc, cntb, flag);
  dinv_kernel<<<(NN + 255) / 256, 256, 0, stream>>>(deg, dinv);
  scan_kernel<<<1, 1024, 0, stream>>>(csrc, row_ptr, cursor);
  fill_kernel<<<(NE + 255) / 256, 256, 0, stream>>>(eidx, dinv, cursor, colA, wgtA, flag);
  v0init_kernel<<<(NN * 64 + 255) / 256, 256, 0, stream>>>(batch, V0, flag);

  // ---- APPNP, transposed: propagate 64-wide pooling coefficients ----
  for (int h = 0; h < 16; ++h) {
    const float* vin = (h & 1) ? V1 : V0;
    float* vout = (h & 1) ? V0 : V1;
    hop_kernel<<<(NN * 64 + 255) / 256, 256, 0, stream>>>(vin, vout, row_ptr, colA,
                                                          wgtA, dinv, batch, flag);
  }

  // ---- BiGRU (fused gi + recurrent + pooling), dir-decoupled ----
  gru_kernel<<<512, 192, GRU_LDS_BYTES, stream>>>(
      seq, wih_f, whh_f, bih_f, bhh_f, wih_b, whh_b, bih_b, bhh_b, hbuf, y_seq);

  // ---- seq MLP: 1024 -> 512 -> 256 -> 14 (writes d_out) ----
  mlp_layer_kernel<<<(64 * 512 + 255) / 256, 256, 0, stream>>>(y_seq, ms_w0, ms_b0, sh1,
                                                               64, 512, 1024, 1, 0);
  mlp_layer_kernel<<<(64 * 256 + 255) / 256, 256, 0, stream>>>(sh1, ms_w1, ms_b1, sh2,
                                                               64, 256, 512, 1, 0);
  mlp_layer_kernel<<<(64 * NCLS + 255) / 256, 256, 0, stream>>>(sh2, ms_w2, ms_b2, out,
                                                                64, NCLS, 256, 0, 0);

  // ---- pooled = (S^T x) / cnt ; after 16 hops result is in V0 ----
  spmm_kernel<<<(768 * 64) / 256, 256, 0, stream>>>(V0, x, part);
  reduce_pool_kernel<<<(64 * DF + 255) / 256, 256, 0, stream>>>(part, cntb, pooled);

  // ---- graph MLP: 768 -> 384 -> 192 -> 14 (accumulates into d_out) ----
  mlp_layer_kernel<<<(64 * 384 + 255) / 256, 256, 0, stream>>>(pooled, mg_w0, mg_b0, gh1,
                                                               64, 384, 768, 1, 0);
  mlp_layer_kernel<<<(64 * 192 + 255) / 256, 256, 0, stream>>>(gh1, mg_w1, mg_b1, gh2,
                                                               64, 192, 384, 1, 0);
  mlp_layer_kernel<<<(64 * NCLS + 255) / 256, 256, 0, stream>>>(gh2, mg_w2, mg_b2, out,
                                                                64, NCLS, 192, 0, 1);
  (void)in_sizes; (void)n_in; (void)out_size; (void)ws_size;
}

// Round 2
// 1553.030 us; speedup vs baseline: 1.1215x; 1.0025x over previous
//
#include <hip/hip_runtime.h>
#include <stdint.h>

#define ALPHA 0.1f
#define NN 20000
#define DF 768
#define NE 200000
#define NB 64
#define TSEQ 128
#define SF 128
#define HS 512
#define NCLS 14

typedef __attribute__((ext_vector_type(8))) short short8;
typedef __attribute__((ext_vector_type(4))) float f32x4;
typedef __attribute__((ext_vector_type(4))) unsigned int u32x4;

// ---------------- workspace layout (bytes) ----------------
#define OFF_DEG     0u           // int[20000]
#define OFF_CSRC    80000u       // int[20000]
#define OFF_CNTB    160000u      // int[64]
#define OFF_FLAG64  176640u      // int[1] : 1 if indices are int64
#define ZERO_INTS   44161u       // zero [0, 176644)
#define OFF_ROWPTR  176896u      // int[20001]
#define OFF_CURSOR  257024u      // int[20000]
#define OFF_DINV    337024u      // float[20000]
#define OFF_COL     417024u      // int[200000]
#define OFF_WGT     1217024u     // float[200000]
#define OFF_V0      2017280u     // float[20000*64]
#define OFF_V1      7137280u     // float[20000*64]
#define OFF_HBUF    12257280u    // u32 [2][2][64][256]  (2 x bf16 h, untagged)
#define OFF_HFLAG   12519424u    // u32 [2][2][8][64]    (rank flags = step tag)
#define OFF_YSEQ    12781568u    // float[64*1024]
#define OFF_SH1     13043712u    // float[64*512]
#define OFF_SH2     13174784u    // float[64*256]
#define OFF_PART    13240320u    // float[16][64][768]
#define OFF_POOL    16386048u    // float[64*768]
#define OFF_GH1     16582656u    // float[64*384]
#define OFF_GH2     16680960u    // float[64*192]

__device__ __forceinline__ unsigned short f2b(float f) {
  union { float f; unsigned u; } v; v.f = f;
  unsigned u = v.u;
  return (unsigned short)((u + 0x7FFFu + ((u >> 16) & 1u)) >> 16);
}

__device__ __forceinline__ int idx_at(const int* p, long long i, int mode64) {
  return mode64 ? p[2*i] : p[i];   // little-endian low word
}

// ---------------- small utility kernels ----------------
__global__ void zero_ints_kernel(int* p, int n) {
  int i = blockIdx.x * blockDim.x + threadIdx.x;
  if (i < n) p[i] = 0;
}

__global__ void detect_i64_kernel(const int* e, int* flag) {
  if (threadIdx.x == 0 && blockIdx.x == 0) {
    int all0 = 1;
    for (int i = 0; i < 256; ++i) if (e[2*i + 1] != 0) { all0 = 0; break; }
    *flag = all0;
  }
}

__global__ void hist_kernel(const int* e, const int* batch, int* deg, int* csrc,
                            int* cntb, const int* flag) {
  int i = blockIdx.x * blockDim.x + threadIdx.x;
  int m = *flag;
  if (i < NE) {
    int s = idx_at(e, i, m);
    int d = idx_at(e, (long long)NE + i, m);
    atomicAdd(&csrc[s], 1);
    atomicAdd(&deg[d], 1);
  }
  if (i < NN) atomicAdd(&cntb[idx_at(batch, i, m)], 1);
}

__global__ void dinv_kernel(const int* deg, float* dinv) {
  int i = blockIdx.x * blockDim.x + threadIdx.x;
  if (i < NN) dinv[i] = rsqrtf((float)(deg[i] + 1));   // +1 self loop, >=1
}

__global__ void scan_kernel(const int* cnt, int* row_ptr, int* cursor) {
  __shared__ int sA[1024], sB[1024];
  int tid = threadIdx.x;
  int carry = 0;
  const int nch = (NN + 1023) / 1024;
  for (int c = 0; c < nch; ++c) {
    int i = c * 1024 + tid;
    int v = (i < NN) ? cnt[i] : 0;
    sA[tid] = v;
    __syncthreads();
    int* src = sA; int* dst = sB;
    for (int off = 1; off < 1024; off <<= 1) {
      dst[tid] = src[tid] + (tid >= off ? src[tid - off] : 0);
      __syncthreads();
      int* t = src; src = dst; dst = t;
    }
    if (i < NN) { int ex = carry + src[tid] - v; row_ptr[i] = ex; cursor[i] = ex; }
    carry += src[1023];
    __syncthreads();
  }
  if (tid == 0) row_ptr[NN] = carry;
}

__global__ void fill_kernel(const int* e, const float* dinv, int* cursor,
                            int* colA, float* wgt, const int* flag) {
  int i = blockIdx.x * blockDim.x + threadIdx.x;
  if (i >= NE) return;
  int m = *flag;
  int s = idx_at(e, i, m);
  int d = idx_at(e, (long long)NE + i, m);
  int pos = atomicAdd(&cursor[s], 1);
  colA[pos] = d;
  wgt[pos] = dinv[s] * dinv[d];
}

__global__ void v0init_kernel(const int* batch, float* v0, const int* flag) {
  int i = blockIdx.x * blockDim.x + threadIdx.x;
  if (i >= NN * 64) return;
  int n = i >> 6, b = i & 63;
  v0[i] = (idx_at(batch, n, *flag) == b) ? 1.0f : 0.0f;
}

// one wave per node, lane = graph id (64 == wave width); 4-edge ILP
__global__ void hop_kernel(const float* __restrict__ vin, float* __restrict__ vout,
                           const int* __restrict__ row_ptr, const int* __restrict__ colA,
                           const float* __restrict__ wgt, const float* __restrict__ dinv,
                           const int* __restrict__ batch, const int* __restrict__ flag) {
  int wid = (blockIdx.x * blockDim.x + threadIdx.x) >> 6;
  int lane = threadIdx.x & 63;
  if (wid >= NN) return;
  float di = dinv[wid];
  float acc = di * di * vin[wid * 64 + lane];
  int e0 = row_ptr[wid], e1 = row_ptr[wid + 1];
  int e = e0;
  for (; e + 4 <= e1; e += 4) {
    int c0 = colA[e], c1 = colA[e + 1], c2 = colA[e + 2], c3 = colA[e + 3];
    float w0 = wgt[e], w1 = wgt[e + 1], w2 = wgt[e + 2], w3 = wgt[e + 3];
    float v0 = vin[(size_t)c0 * 64 + lane];
    float v1 = vin[(size_t)c1 * 64 + lane];
    float v2 = vin[(size_t)c2 * 64 + lane];
    float v3 = vin[(size_t)c3 * 64 + lane];
    acc += w0 * v0 + w1 * v1 + w2 * v2 + w3 * v3;
  }
  for (; e < e1; ++e) acc += wgt[e] * vin[(size_t)colA[e] * 64 + lane];
  float y0 = (idx_at(batch, wid, *flag) == lane) ? ALPHA : 0.0f;
  vout[wid * 64 + lane] = (1.0f - ALPHA) * acc + y0;
}

// pooled_unnorm partials: 48 f-tiles x 16 node-chunks, lane = graph id
__global__ void spmm_kernel(const float* __restrict__ S, const float* __restrict__ x,
                            float* __restrict__ partial) {
  int wid = (blockIdx.x * blockDim.x + threadIdx.x) >> 6;   // 768 waves
  int lane = threadIdx.x & 63;
  int ft = wid % 48, ch = wid / 48;
  if (ch >= 16) return;
  int f0 = ft * 16;
  int n0 = ch * 1250, n1 = n0 + 1250;
  float acc[16];
#pragma unroll
  for (int f = 0; f < 16; ++f) acc[f] = 0.0f;
  for (int n = n0; n < n1; ++n) {
    float sv = S[n * 64 + lane];
    const float* xr = x + (size_t)n * DF + f0;
#pragma unroll
    for (int f = 0; f < 16; ++f) acc[f] += sv * xr[f];
  }
  float* pr = partial + ((size_t)(ch * 64 + lane)) * DF + f0;
#pragma unroll
  for (int f = 0; f < 16; ++f) pr[f] = acc[f];
}

__global__ void reduce_pool_kernel(const float* __restrict__ partial, const int* __restrict__ cntb,
                                   float* __restrict__ pooled) {
  int i = blockIdx.x * blockDim.x + threadIdx.x;
  if (i >= 64 * DF) return;
  int b = i / DF, f = i - b * DF;
  float s = 0.0f;
  for (int c = 0; c < 16; ++c) s += partial[((size_t)(c * 64 + b)) * DF + f];
  int cnt = cntb[b]; if (cnt < 1) cnt = 1;
  pooled[i] = s / (float)cnt;
}

// C[M,N] = act(A[M,K] @ W[N,K]^T + bias), optionally accumulate into C
__global__ void mlp_layer_kernel(const float* __restrict__ A, const float* __restrict__ W,
                                 const float* __restrict__ bias, float* __restrict__ C,
                                 int M, int N, int K, int relu, int accum) {
  int i = blockIdx.x * blockDim.x + threadIdx.x;
  if (i >= M * N) return;
  int mrow = i / N, n = i - mrow * N;
  float acc = bias[n];
  const float4* a4 = (const float4*)(A + (size_t)mrow * K);
  const float4* w4 = (const float4*)(W + (size_t)n * K);
  int k4 = K >> 2;
#pragma unroll 4
  for (int k = 0; k < k4; ++k) {
    float4 av = a4[k], wv = w4[k];
    acc += av.x * wv.x + av.y * wv.y + av.z * wv.z + av.w * wv.w;
  }
  if (relu) acc = fmaxf(acc, 0.0f);
  if (accum) C[i] += acc; else C[i] = acc;
}

// ---------------- GRU recurrent kernel (dir-decoupled, flag exchange) -------
// 512 blocks x 192 threads: blockIdx = d*256 + g*32 + rk.
// Exchange protocol (release/acquire at MALL):
//   producer: pack 2 bf16/u32, global_store sc0 sc1 (bypass L1/L2 -> MALL),
//             s_waitcnt vmcnt(0)  [release: data ack'd],
//             store rank flag = t+1 (sc0 sc1).
//   consumer: poll ONLY 64 flag words/round (one dword per lane; ~256 B/block
//             /round vs 16 KB/round of the old tagged-word scheme -> kills the
//             MALL polling storm), then bulk-load the 8 KB h slab ONCE
//             (sc0 sc1; L2 may hold stale lines, MALL is the coherence point),
//             scatter into LDS. Flags are zeroed every launch so stale tags
//             from a previous graph replay can never pre-satisfy a poll.
// Slot reuse (double buffer on t&1) is safe 2-deep: any rank storing t+3
// implies every rank finished reading t+1 (it had to gather t+2 first).
#define GRU_LDS_BYTES 74624   // 48*648*2 + 8*648*2 + 64*8*4

__global__ __launch_bounds__(192, 1) void gru_kernel(
    const float* __restrict__ seq,
    const float* __restrict__ wih_f, const float* __restrict__ whh_f,
    const float* __restrict__ bih_f, const float* __restrict__ bhh_f,
    const float* __restrict__ wih_b, const float* __restrict__ whh_b,
    const float* __restrict__ bih_b, const float* __restrict__ bhh_b,
    unsigned* __restrict__ hbuf, unsigned* __restrict__ hflag,
    float* __restrict__ y_seq) {
  extern __shared__ char smem_raw[];
  unsigned short* W1 = (unsigned short*)smem_raw;     // [48][648]
  unsigned short* hl = W1 + 48 * 648;                 // [8][648]
  float* ghs = (float*)(hl + 8 * 648);                // [64][8]

  const int tid = threadIdx.x;            // 0..191
  const int wave = tid >> 6, lane = tid & 63;
  const int quad = lane >> 4, l15 = lane & 15;
  const int d  = blockIdx.x >> 8;         // 0 fwd, 1 bwd
  const int g  = (blockIdx.x >> 5) & 7;   // 8 groups
  const int rk = blockIdx.x & 31;         // 32 ranks
  const int seqbase = g * 8;
  const int c0 = rk * 16;

  const float* WHHd = d ? whh_b : whh_f;
  const float* WIHd = d ? wih_b : wih_f;
  const float* BIHd = d ? bih_b : bih_f;
  const float* BHHd = d ? bhh_b : bhh_f;

  // ---- stationary weights -> LDS (fp32 -> bf16), one direction ----
  for (int i = tid; i < 48 * 640; i += 192) {
    int rrow = i / 640;
    int c = i - rrow * 640;
    int gcol = (rrow < 16) ? (c0 + rrow)
             : (rrow < 32) ? (512 + c0 + (rrow - 16))
                           : (1024 + c0 + (rrow - 32));
    float val = (c < 512) ? WHHd[gcol * 512 + c] : WIHd[gcol * 128 + (c - 512)];
    W1[rrow * 648 + c] = f2b(val);
  }
  // ---- hl init: h(0)=0; stage x(0) ----
  for (int i = tid; i < 8 * 512; i += 192) {
    int s = i >> 9, c = i & 511;
    hl[s * 648 + c] = 0;
  }
  {
    int tt = d ? 127 : 0;
    for (int i = tid; i < 8 * 128; i += 192) {
      int s = i >> 7, k = i & 127;
      hl[s * 648 + 512 + k] =
          f2b(seq[(size_t)(seqbase + s) * (TSEQ * SF) + tt * SF + k]);
    }
  }

  float b_r = 0, b_z = 0, b_in = 0, b_hn = 0;
  float hprev = 0, msum = 0, mx = -1e30f;
  const int seq_i = (tid >> 4) & 7, col_i = tid & 15;
  if (tid < 128) {
    b_r  = BIHd[c0 + col_i] + BHHd[c0 + col_i];
    b_z  = BIHd[512 + c0 + col_i] + BHHd[512 + c0 + col_i];
    b_in = BIHd[1024 + c0 + col_i];
    b_hn = BHHd[1024 + c0 + col_i];
  }
  __syncthreads();

  // wave role: 0=r, 1=z, 2=n. Dual accumulators halve the dependent-MFMA chain.
  auto do_gemm = [&]() {
    const unsigned short* arow = hl + (l15 & 7) * 648 + quad * 8;  // rows 8-15 dup rows 0-7 (discarded)
    const unsigned short* brow = W1 + (wave * 16 + l15) * 648 + quad * 8;
    if (wave < 2) {           // r or z: fused K=640 over [h|x]
      f32x4 a0 = {0, 0, 0, 0}, a1 = {0, 0, 0, 0};
#pragma unroll
      for (int kc = 0; kc < 20; kc += 2) {
        a0 = __builtin_amdgcn_mfma_f32_16x16x32_bf16(
            *(const short8*)(arow + kc * 32), *(const short8*)(brow + kc * 32),
            a0, 0, 0, 0);
        a1 = __builtin_amdgcn_mfma_f32_16x16x32_bf16(
            *(const short8*)(arow + (kc + 1) * 32), *(const short8*)(brow + (kc + 1) * 32),
            a1, 0, 0, 0);
      }
      f32x4 accH = a0 + a1;
      float* gd = ghs + (wave * 16 + l15) * 8;
#pragma unroll
      for (int rr = 0; rr < 4; ++rr) { int m = quad * 4 + rr; if (m < 8) gd[m] = accH[rr]; }
    } else {                  // n: h-part (K=512) and x-part (K=128) separate
      f32x4 a0 = {0, 0, 0, 0}, a1 = {0, 0, 0, 0}, accX = {0, 0, 0, 0};
#pragma unroll
      for (int kc = 0; kc < 16; kc += 2) {
        a0 = __builtin_amdgcn_mfma_f32_16x16x32_bf16(
            *(const short8*)(arow + kc * 32), *(const short8*)(brow + kc * 32),
            a0, 0, 0, 0);
        a1 = __builtin_amdgcn_mfma_f32_16x16x32_bf16(
            *(const short8*)(arow + (kc + 1) * 32), *(const short8*)(brow + (kc + 1) * 32),
            a1, 0, 0, 0);
      }
#pragma unroll
      for (int kc = 0; kc < 4; ++kc)
        accX = __builtin_amdgcn_mfma_f32_16x16x32_bf16(
            *(const short8*)(arow + 512 + kc * 32), *(const short8*)(brow + 512 + kc * 32),
            accX, 0, 0, 0);
      f32x4 accH = a0 + a1;
      float* gdh = ghs + (32 + l15) * 8;
      float* gdx = ghs + (48 + l15) * 8;
#pragma unroll
      for (int rr = 0; rr < 4; ++rr) {
        int m = quad * 4 + rr;
        if (m < 8) { gdh[m] = accH[rr]; gdx[m] = accX[rr]; }
      }
    }
  };

  // gather h(tagexp) into hl + stage x(t_x); run by all 192 threads
  auto do_gather_stage = [&](int t_x, int slot, unsigned tagexp) {
    // stage x first (independent global loads overlap the flag-poll)
    {
      int tt = d ? (127 - t_x) : t_x;
#pragma unroll
      for (int j = 0; j < 6; ++j) {
        int flat = tid + 192 * j;
        if (flat < 1024) {
          int s = flat >> 7, k = flat & 127;
          hl[s * 648 + 512 + k] =
              f2b(seq[(size_t)(seqbase + s) * (TSEQ * SF) + tt * SF + k]);
        }
      }
    }
    // ---- poll 64 rank flags (lane l watches flag[l]) ----
    const unsigned* fp = hflag + ((size_t)(slot * 2 + d) * 8 + g) * 64 + lane;
    int guard = 0;
    unsigned fv;
    for (;;) {
      asm volatile("global_load_dword %0, %1, off sc0 sc1"
                   : "=v"(fv) : "v"(fp) : "memory");
      asm volatile("s_waitcnt vmcnt(0)" ::: "memory");
      __builtin_amdgcn_sched_barrier(0);
      if (__all(fv == tagexp)) break;
      if (++guard > (1 << 20)) break;
      __builtin_amdgcn_s_sleep(1);
    }
    // ---- bulk data load: 2048 u32 (8 seqs x 256 words), once ----
    const unsigned* db = hbuf + (size_t)((slot * 2 + d) * 64 + seqbase) * 256;
    u32x4 w0, w1, w2;
    asm volatile("global_load_dwordx4 %0, %1, off sc0 sc1"
                 : "=v"(w0) : "v"(db + (unsigned)tid * 4) : "memory");
    asm volatile("global_load_dwordx4 %0, %1, off sc0 sc1"
                 : "=v"(w1) : "v"(db + (unsigned)(tid + 192) * 4) : "memory");
    if (tid < 128)
      asm volatile("global_load_dwordx4 %0, %1, off sc0 sc1"
                   : "=v"(w2) : "v"(db + (unsigned)(tid + 384) * 4) : "memory");
    asm volatile("s_waitcnt vmcnt(0)" ::: "memory");
    __builtin_amdgcn_sched_barrier(0);
    {
      int flat = tid * 4;
      unsigned* dp = (unsigned*)hl + (flat >> 8) * 324 + (flat & 255);
      dp[0] = w0[0]; dp[1] = w0[1]; dp[2] = w0[2]; dp[3] = w0[3];
    }
    {
      int flat = (tid + 192) * 4;
      unsigned* dp = (unsigned*)hl + (flat >> 8) * 324 + (flat & 255);
      dp[0] = w1[0]; dp[1] = w1[1]; dp[2] = w1[2]; dp[3] = w1[3];
    }
    if (tid < 128) {
      int flat = (tid + 384) * 4;
      unsigned* dp = (unsigned*)hl + (flat >> 8) * 324 + (flat & 255);
      dp[0] = w2[0]; dp[1] = w2[1]; dp[2] = w2[2]; dp[3] = w2[3];
    }
  };

  for (int t = 0; t < 128; ++t) {
    do_gemm();
    __syncthreads();
    if (tid < 128) {
      const float* gd = ghs;
      float gr = gd[col_i * 8 + seq_i];
      float gz = gd[(16 + col_i) * 8 + seq_i];
      float gh = gd[(32 + col_i) * 8 + seq_i];
      float gx = gd[(48 + col_i) * 8 + seq_i];
      float r = 1.0f / (1.0f + __expf(-(gr + b_r)));
      float z = 1.0f / (1.0f + __expf(-(gz + b_z)));
      float narg = gx + b_in + r * (gh + b_hn);
      float e2 = __expf(-2.0f * fabsf(narg));
      float nt = (1.0f - e2) / (1.0f + e2);
      nt = (narg < 0.0f) ? -nt : nt;
      float h2 = (1.0f - z) * nt + z * hprev;
      hprev = h2; msum += h2; mx = fmaxf(mx, h2);
      if (t < 127) {
        // pack 2 cols per u32 (even lane = low, odd neighbor = high)
        unsigned me = f2b(h2);
        unsigned nb = (unsigned)__shfl_xor((int)me, 1);
        if ((col_i & 1) == 0) {
          unsigned word = (me & 0xFFFFu) | (nb << 16);
          unsigned* dp = hbuf +
              ((size_t)(((t + 1) & 1) * 2 + d) * 64 + seqbase + seq_i) * 256 +
              (unsigned)((c0 + col_i) >> 1);
          asm volatile("global_store_dword %0, %1, off sc0 sc1"
                       :: "v"(dp), "v"(word) : "memory");
        }
        asm volatile("s_waitcnt vmcnt(0)" ::: "memory");   // release: data ack'd at MALL
        if (lane == 0) {   // wave0 covers seqs 0-3, wave1 covers seqs 4-7
          unsigned* fpo = hflag +
              ((size_t)(((t + 1) & 1) * 2 + d) * 8 + g) * 64 + rk * 2 + wave;
          unsigned tv = (unsigned)(t + 1);
          asm volatile("global_store_dword %0, %1, off sc0 sc1"
                       :: "v"(fpo), "v"(tv) : "memory");
        }
      }
    }
    if (t < 127) do_gather_stage(t + 1, (t + 1) & 1, (unsigned)(t + 1));
    __syncthreads();
  }

  if (tid < 128) {   // seq1 + seq2 = mean + max over T
    y_seq[(size_t)(seqbase + seq_i) * 1024 + d * 512 + c0 + col_i] =
        msum * (1.0f / 128.0f) + mx;
  }
}

// ---------------- launcher ----------------
extern "C" void kernel_launch(void* const* d_in, const int* in_sizes, int n_in,
                              void* d_out, int out_size, void* d_ws, size_t ws_size,
                              hipStream_t stream) {
  const float* x      = (const float*)d_in[0];
  const int*   eidx   = (const int*)d_in[1];
  const float* seq    = (const float*)d_in[2];
  const int*   batch  = (const int*)d_in[3];
  const float* wih_f  = (const float*)d_in[4];
  const float* whh_f  = (const float*)d_in[5];
  const float* bih_f  = (const float*)d_in[6];
  const float* bhh_f  = (const float*)d_in[7];
  const float* wih_b  = (const float*)d_in[8];
  const float* whh_b  = (const float*)d_in[9];
  const float* bih_b  = (const float*)d_in[10];
  const float* bhh_b  = (const float*)d_in[11];
  const float* mg_w0  = (const float*)d_in[12];
  const float* mg_b0  = (const float*)d_in[13];
  const float* mg_w1  = (const float*)d_in[14];
  const float* mg_b1  = (const float*)d_in[15];
  const float* mg_w2  = (const float*)d_in[16];
  const float* mg_b2  = (const float*)d_in[17];
  const float* ms_w0  = (const float*)d_in[18];
  const float* ms_b0  = (const float*)d_in[19];
  const float* ms_w1  = (const float*)d_in[20];
  const float* ms_b1  = (const float*)d_in[21];
  const float* ms_w2  = (const float*)d_in[22];
  const float* ms_b2  = (const float*)d_in[23];
  float* out = (float*)d_out;
  char* ws = (char*)d_ws;

  int*   deg     = (int*)(ws + OFF_DEG);
  int*   csrc    = (int*)(ws + OFF_CSRC);
  int*   cntb    = (int*)(ws + OFF_CNTB);
  int*   flag    = (int*)(ws + OFF_FLAG64);
  int*   row_ptr = (int*)(ws + OFF_ROWPTR);
  int*   cursor  = (int*)(ws + OFF_CURSOR);
  float* dinv    = (float*)(ws + OFF_DINV);
  int*   colA    = (int*)(ws + OFF_COL);
  float* wgtA    = (float*)(ws + OFF_WGT);
  float* V0      = (float*)(ws + OFF_V0);
  float* V1      = (float*)(ws + OFF_V1);
  unsigned* hbuf = (unsigned*)(ws + OFF_HBUF);
  unsigned* hflag= (unsigned*)(ws + OFF_HFLAG);
  float* y_seq   = (float*)(ws + OFF_YSEQ);
  float* sh1     = (float*)(ws + OFF_SH1);
  float* sh2     = (float*)(ws + OFF_SH2);
  float* part    = (float*)(ws + OFF_PART);
  float* pooled  = (float*)(ws + OFF_POOL);
  float* gh1     = (float*)(ws + OFF_GH1);
  float* gh2     = (float*)(ws + OFF_GH2);

  hipFuncSetAttribute((const void*)gru_kernel,
                      hipFuncAttributeMaxDynamicSharedMemorySize, GRU_LDS_BYTES);

  // ---- graph prep (CSR for A^T, degrees, batch counts) ----
  zero_ints_kernel<<<(ZERO_INTS + 255) / 256, 256, 0, stream>>>((int*)ws, (int)ZERO_INTS);
  zero_ints_kernel<<<8, 256, 0, stream>>>((int*)(ws + OFF_HFLAG), 2048);  // rank flags
  detect_i64_kernel<<<1, 64, 0, stream>>>(eidx, flag);
  hist_kernel<<<(NE + 255) / 256, 256, 0, stream>>>(eidx, batch, deg, csrc, cntb, flag);
  dinv_kernel<<<(NN + 255) / 256, 256, 0, stream>>>(deg, dinv);
  scan_kernel<<<1, 1024, 0, stream>>>(csrc, row_ptr, cursor);
  fill_kernel<<<(NE + 255) / 256, 256, 0, stream>>>(eidx, dinv, cursor, colA, wgtA, flag);
  v0init_kernel<<<(NN * 64 + 255) / 256, 256, 0, stream>>>(batch, V0, flag);

  // ---- APPNP, transposed: propagate 64-wide pooling coefficients ----
  for (int h = 0; h < 16; ++h) {
    const float* vin = (h & 1) ? V1 : V0;
    float* vout = (h & 1) ? V0 : V1;
    hop_kernel<<<(NN * 64 + 255) / 256, 256, 0, stream>>>(vin, vout, row_ptr, colA,
                                                          wgtA, dinv, batch, flag);
  }

  // ---- BiGRU (fused gi + recurrent + pooling), dir-decoupled ----
  gru_kernel<<<512, 192, GRU_LDS_BYTES, stream>>>(
      seq, wih_f, whh_f, bih_f, bhh_f, wih_b, whh_b, bih_b, bhh_b, hbuf, hflag, y_seq);

  // ---- seq MLP: 1024 -> 512 -> 256 -> 14 (writes d_out) ----
  mlp_layer_kernel<<<(64 * 512 + 255) / 256, 256, 0, stream>>>(y_seq, ms_w0, ms_b0, sh1,
                                                               64, 512, 1024, 1, 0);
  mlp_layer_kernel<<<(64 * 256 + 255) / 256, 256, 0, stream>>>(sh1, ms_w1, ms_b1, sh2,
                                                               64, 256, 512, 1, 0);
  mlp_layer_kernel<<<(64 * NCLS + 255) / 256, 256, 0, stream>>>(sh2, ms_w2, ms_b2, out,
                                                                64, NCLS, 256, 0, 0);

  // ---- pooled = (S^T x) / cnt ; after 16 hops result is in V0 ----
  spmm_kernel<<<(768 * 64) / 256, 256, 0, stream>>>(V0, x, part);
  reduce_pool_kernel<<<(64 * DF + 255) / 256, 256, 0, stream>>>(part, cntb, pooled);

  // ---- graph MLP: 768 -> 384 -> 192 -> 14 (accumulates into d_out) ----
  mlp_layer_kernel<<<(64 * 384 + 255) / 256, 256, 0, stream>>>(pooled, mg_w0, mg_b0, gh1,
                                                               64, 384, 768, 1, 0);
  mlp_layer_kernel<<<(64 * 192 + 255) / 256, 256, 0, stream>>>(gh1, mg_w1, mg_b1, gh2,
                                                               64, 192, 384, 1, 0);
  mlp_layer_kernel<<<(64 * NCLS + 255) / 256, 256, 0, stream>>>(gh2, mg_w2, mg_b2, out,
                                                                64, NCLS, 192, 0, 1);
  (void)in_sizes; (void)n_in; (void)out_size; (void)ws_size;
}